// Round 2
// baseline (480.071 us; speedup 1.0000x reference)
//
#include <hip/hip_runtime.h>
#include <math.h>

// PANLoss: dice(regions) + 0.5*dice(kernels) + 0.25*(agg + dis)
//
// R2 strategy: per-thread private LDS bins indexed directly by label.
// LDS layout: bins[quantity][bin][tid] with quantity in ws order:
//   q 0..8   ct[seg]   (count, tlab)
//   q 9..17  ck[seg]   (count, klab)
//   q 18..26 St[seg]   (sum s2 over tlab==seg)
//   q 27..35 Sk[seg]   (sum s2 over klab==seg)
//   q 36..44 Ss[seg]   (sum s2 over tlab==seg && klab==seg)
// bank = ((q*9+bin)*256 + tid) % 32 == tid % 32  -> conflict-free.
// Bins are tid-private -> ds_add_f32 has zero contention.
//
// ws per batch (NACC=51): [0..44] as above, [45..47] region dice pg/pp/gg,
// [48..50] kernel dice pg/pp/gg.

#define NSEG 9
#define NACC 51
#define NBATCH 16
#define EPSF 1e-5f
#define GX 100   // 100*256 threads per batch; 102400 float4 / 25600 = exactly 4 iters

__device__ __forceinline__ float wave_reduce_sum(float v) {
#pragma unroll
    for (int off = 32; off > 0; off >>= 1)
        v += __shfl_down(v, off, 64);
    return v;
}

__device__ __forceinline__ float sigm(float x) {
    return 1.0f / (1.0f + __expf(-x));
}

__global__ __launch_bounds__(256) void pan_main(
    const float* __restrict__ pred_r, const float* __restrict__ gt_r,
    const float* __restrict__ pred_k, const float* __restrict__ gt_k,
    const float* __restrict__ sim,
    const int* __restrict__ tlab, const int* __restrict__ klab,
    float* __restrict__ ws, int npix)
{
    __shared__ float bins[45 * 256];  // 46080 B

    const int tid = threadIdx.x;
    const int b = blockIdx.y;

    // zero private bins
#pragma unroll
    for (int q = 0; q < 45; ++q)
        bins[q * 256 + tid] = 0.0f;
    __syncthreads();

    const int nvec = npix >> 2;
    const long long base = (long long)b * npix;
    const long long sbase = (long long)b * 4 * npix;

    const float4* pr4 = (const float4*)(pred_r + base);
    const float4* gr4 = (const float4*)(gt_r + base);
    const float4* pk4 = (const float4*)(pred_k + base);
    const float4* gk4 = (const float4*)(gt_k + base);
    const float4* c0_4 = (const float4*)(sim + sbase);
    const float4* c1_4 = (const float4*)(sim + sbase + npix);
    const float4* c2_4 = (const float4*)(sim + sbase + 2LL * npix);
    const float4* c3_4 = (const float4*)(sim + sbase + 3LL * npix);
    const int4* tl4 = (const int4*)(tlab + base);
    const int4* kl4 = (const int4*)(klab + base);

    float rpg = 0.0f, rpp = 0.0f, rgg = 0.0f;
    float kpg = 0.0f, kpp = 0.0f, kgg = 0.0f;

#define DO_PIX(TL, KL, S2) {                                   \
        float s2m = ((TL) == (KL)) ? (S2) : 0.0f;              \
        float* bt = bins + (TL) * 256 + tid;                   \
        float* bk = bins + (KL) * 256 + tid;                   \
        atomicAdd(bt, 1.0f);               /* ct   */          \
        atomicAdd(bk + 9 * 256, 1.0f);     /* ck   */          \
        atomicAdd(bt + 18 * 256, (S2));    /* St   */          \
        atomicAdd(bk + 27 * 256, (S2));    /* Sk   */          \
        atomicAdd(bt + 36 * 256, s2m);     /* Ss   */          \
    }

    for (int i = blockIdx.x * blockDim.x + tid; i < nvec;
         i += gridDim.x * blockDim.x) {
        float4 pr = pr4[i], gr = gr4[i], pk = pk4[i], gk = gk4[i];
        float4 c0 = c0_4[i], c1 = c1_4[i], c2 = c2_4[i], c3 = c3_4[i];
        int4 tl = tl4[i], kl = kl4[i];

        // dice sums
        {
            float p;
            p = sigm(pr.x); rpg += p * gr.x; rpp += p * p; rgg += gr.x * gr.x;
            p = sigm(pr.y); rpg += p * gr.y; rpp += p * p; rgg += gr.y * gr.y;
            p = sigm(pr.z); rpg += p * gr.z; rpp += p * p; rgg += gr.z * gr.z;
            p = sigm(pr.w); rpg += p * gr.w; rpp += p * p; rgg += gr.w * gr.w;
            p = sigm(pk.x); kpg += p * gk.x; kpp += p * p; kgg += gk.x * gk.x;
            p = sigm(pk.y); kpg += p * gk.y; kpp += p * p; kgg += gk.y * gk.y;
            p = sigm(pk.z); kpg += p * gk.z; kpp += p * p; kgg += gk.z * gk.z;
            p = sigm(pk.w); kpg += p * gk.w; kpp += p * p; kgg += gk.w * gk.w;
        }

        // per-pixel squared feature norm
        float s2x = c0.x * c0.x + c1.x * c1.x + c2.x * c2.x + c3.x * c3.x;
        float s2y = c0.y * c0.y + c1.y * c1.y + c2.y * c2.y + c3.y * c3.y;
        float s2z = c0.z * c0.z + c1.z * c1.z + c2.z * c2.z + c3.z * c3.z;
        float s2w = c0.w * c0.w + c1.w * c1.w + c2.w * c2.w + c3.w * c3.w;

        DO_PIX(tl.x, kl.x, s2x);
        DO_PIX(tl.y, kl.y, s2y);
        DO_PIX(tl.z, kl.z, s2z);
        DO_PIX(tl.w, kl.w, s2w);
    }
#undef DO_PIX

    __syncthreads();

    const int lane = tid & 63;
    const int wv = tid >> 6;

    // reduce the 45 binned quantities: each wave takes q = wv, wv+4, ...
    for (int q = wv; q < 45; q += 4) {
        const float4 v = *(const float4*)&bins[q * 256 + (lane << 2)];
        float s = (v.x + v.y) + (v.z + v.w);
        s = wave_reduce_sum(s);
        if (lane == 0) atomicAdd(&ws[b * NACC + q], s);
    }

    // dice sums: wave-reduce, one atomic per wave per quantity
    float r;
    r = wave_reduce_sum(rpg); if (lane == 0) atomicAdd(&ws[b * NACC + 45], r);
    r = wave_reduce_sum(rpp); if (lane == 0) atomicAdd(&ws[b * NACC + 46], r);
    r = wave_reduce_sum(rgg); if (lane == 0) atomicAdd(&ws[b * NACC + 47], r);
    r = wave_reduce_sum(kpg); if (lane == 0) atomicAdd(&ws[b * NACC + 48], r);
    r = wave_reduce_sum(kpp); if (lane == 0) atomicAdd(&ws[b * NACC + 49], r);
    r = wave_reduce_sum(kgg); if (lane == 0) atomicAdd(&ws[b * NACC + 50], r);
}

__global__ __launch_bounds__(64) void pan_finalize(
    const float* __restrict__ ws, float* __restrict__ out)
{
    const int b = threadIdx.x;
    float dice_r = 0.0f, dice_k = 0.0f, lagg = 0.0f, ldis = 0.0f;

    if (b < NBATCH) {
        const float* w = ws + b * NACC;
        {
            float pg = w[45], pp = w[46], gg = w[47];
            dice_r = 1.0f - (2.0f * pg + EPSF) / ((pp + EPSF) + (gg + EPSF));
            pg = w[48]; pp = w[49]; gg = w[50];
            dice_k = 1.0f - (2.0f * pg + EPSF) / ((pp + EPSF) + (gg + EPSF));
        }
        float a[8];
#pragma unroll
        for (int i = 1; i < NSEG; ++i) {
            float ct = w[i], ck = w[NSEG + i];
            float St = w[2 * NSEG + i], Sk = w[3 * NSEG + i], Ss = w[4 * NSEG + i];
            float inv = 1.0f / (ck + 1.0f);
            float omi = 1.0f - inv;
            float n2 = omi * omi * Ss + (St - Ss) + inv * inv * (Sk - Ss);
            float nrm = sqrtf(n2);
            float d = nrm - 0.5f;  // SIGMA_AGG (no clamp — matches reference)
            lagg += logf(d * d + 1.0f) / (ct + 1.0f);
            float ckd = ck + 0.001f;
            a[i - 1] = Sk / (ckd * ckd);
        }
#pragma unroll
        for (int i = 0; i < 8; ++i) {
#pragma unroll
            for (int j = i + 1; j < 8; ++j) {
                float pair = 3.0f - sqrtf(a[i] + a[j]);  // SIGMA_DIS
                ldis += logf(pair * pair + 1.0f);
            }
        }
        ldis *= (1.0f / 56.0f);  // K_MAX*(K_MAX-1)
    }

    dice_r = wave_reduce_sum(dice_r);
    dice_k = wave_reduce_sum(dice_k);
    lagg = wave_reduce_sum(lagg);
    ldis = wave_reduce_sum(ldis);

    if (threadIdx.x == 0) {
        float loss = dice_r + 0.5f * dice_k + 0.25f * (lagg + ldis);
        out[0] = loss;
        out[1] = dice_r;
        out[2] = dice_k;
        out[3] = lagg;
        out[4] = ldis;
    }
}

extern "C" void kernel_launch(void* const* d_in, const int* in_sizes, int n_in,
                              void* d_out, int out_size, void* d_ws, size_t ws_size,
                              hipStream_t stream) {
    const float* pred_r = (const float*)d_in[0];
    const float* gt_r   = (const float*)d_in[1];
    const float* pred_k = (const float*)d_in[2];
    const float* gt_k   = (const float*)d_in[3];
    const float* sim    = (const float*)d_in[4];
    const int*   tlab   = (const int*)d_in[5];
    const int*   klab   = (const int*)d_in[6];
    float* out = (float*)d_out;
    float* ws  = (float*)d_ws;

    const int npix = in_sizes[0] / NBATCH;  // 640*640 = 409600

    hipMemsetAsync(ws, 0, NBATCH * NACC * sizeof(float), stream);

    dim3 grid(GX, NBATCH);
    pan_main<<<grid, 256, 0, stream>>>(pred_r, gt_r, pred_k, gt_k, sim,
                                       tlab, klab, ws, npix);
    pan_finalize<<<1, 64, 0, stream>>>(ws, out);
}

// Round 3
// 297.458 us; speedup vs baseline: 1.6139x; 1.6139x over previous
//
#include <hip/hip_runtime.h>
#include <math.h>

// PANLoss: dice(regions) + 0.5*dice(kernels) + 0.25*(agg + dis)
//
// R3: register accumulators (R1 structure) with:
//  - __launch_bounds__(256,4): 128-VGPR budget so all 10 loads/iter stay in
//    flight (R1's 52-VGPR cap serialized them -> latency bound).
//  - segment 0 dropped entirely: finalize only reads segments 1..8.
//  - counts via __ballot/__popcll -> scalar pipe; v_cmp mask reused by the
//    cndmask-predicated sums.
//
// ws per batch (NACC=51 floats, slots 0,9,18,27,36 unused/zero):
//   [1..8]   ct[seg]    [10..17] ck[seg]
//   [19..26] St[seg]    [28..35] Sk[seg]   [37..44] Ss[seg]
//   [45..47] regions pg/pp/gg   [48..50] kernels pg/pp/gg

#define NSEG 9
#define NACC 51
#define NBATCH 16
#define EPSF 1e-5f
#define GX 100  // 100*256 threads/batch; 102400 float4 -> exactly 4 iters

__device__ __forceinline__ float wave_reduce_sum(float v) {
#pragma unroll
    for (int off = 32; off > 0; off >>= 1)
        v += __shfl_down(v, off, 64);
    return v;
}

__device__ __forceinline__ float sigm(float x) {
    return 1.0f / (1.0f + __expf(-x));
}

__global__ __launch_bounds__(256, 4) void pan_main(
    const float* __restrict__ pred_r, const float* __restrict__ gt_r,
    const float* __restrict__ pred_k, const float* __restrict__ gt_k,
    const float* __restrict__ sim,
    const int* __restrict__ tlab, const int* __restrict__ klab,
    float* __restrict__ ws, int npix, int niter)
{
    const int tid = threadIdx.x;
    const int b = blockIdx.y;
    const int nvec = npix >> 2;
    const long long base = (long long)b * npix;
    const long long sbase = (long long)b * 4 * npix;

    const float4* pr4 = (const float4*)(pred_r + base);
    const float4* gr4 = (const float4*)(gt_r + base);
    const float4* pk4 = (const float4*)(pred_k + base);
    const float4* gk4 = (const float4*)(gt_k + base);
    const float4* c0_4 = (const float4*)(sim + sbase);
    const float4* c1_4 = (const float4*)(sim + sbase + npix);
    const float4* c2_4 = (const float4*)(sim + sbase + 2LL * npix);
    const float4* c3_4 = (const float4*)(sim + sbase + 3LL * npix);
    const int4* tl4 = (const int4*)(tlab + base);
    const int4* kl4 = (const int4*)(klab + base);

    float St_[8], Sk_[8], Ss_[8];
    unsigned ct_[8], ck_[8];
#pragma unroll
    for (int s = 0; s < 8; ++s) {
        St_[s] = 0.0f; Sk_[s] = 0.0f; Ss_[s] = 0.0f;
        ct_[s] = 0u; ck_[s] = 0u;
    }
    float rpg = 0.0f, rpp = 0.0f, rgg = 0.0f;
    float kpg = 0.0f, kpp = 0.0f, kgg = 0.0f;

    int i = blockIdx.x * blockDim.x + tid;
    const int stride = gridDim.x * blockDim.x;

    for (int t = 0; t < niter; ++t, i += stride) {
        if (i < nvec) {
            float4 pr = pr4[i], gr = gr4[i], pk = pk4[i], gk = gk4[i];
            float4 c0 = c0_4[i], c1 = c1_4[i], c2 = c2_4[i], c3 = c3_4[i];
            int4 tl = tl4[i], kl = kl4[i];

            // dice sums (g in {0,1} so g*g == g)
            {
                float p;
                p = sigm(pr.x); rpg += p * gr.x; rpp += p * p; rgg += gr.x;
                p = sigm(pr.y); rpg += p * gr.y; rpp += p * p; rgg += gr.y;
                p = sigm(pr.z); rpg += p * gr.z; rpp += p * p; rgg += gr.z;
                p = sigm(pr.w); rpg += p * gr.w; rpp += p * p; rgg += gr.w;
                p = sigm(pk.x); kpg += p * gk.x; kpp += p * p; kgg += gk.x;
                p = sigm(pk.y); kpg += p * gk.y; kpp += p * p; kgg += gk.y;
                p = sigm(pk.z); kpg += p * gk.z; kpp += p * p; kgg += gk.z;
                p = sigm(pk.w); kpg += p * gk.w; kpp += p * p; kgg += gk.w;
            }

            float s2x = c0.x * c0.x + c1.x * c1.x + c2.x * c2.x + c3.x * c3.x;
            float s2y = c0.y * c0.y + c1.y * c1.y + c2.y * c2.y + c3.y * c3.y;
            float s2z = c0.z * c0.z + c1.z * c1.z + c2.z * c2.z + c3.z * c3.z;
            float s2w = c0.w * c0.w + c1.w * c1.w + c2.w * c2.w + c3.w * c3.w;

#define DO_COMP(TL, KL, S2)                                          \
            {                                                        \
                bool tt = ((TL) == s);                               \
                bool kk = ((KL) == s);                               \
                ct_[s - 1] += (unsigned)__popcll(__ballot(tt));      \
                ck_[s - 1] += (unsigned)__popcll(__ballot(kk));      \
                St_[s - 1] += tt ? (S2) : 0.0f;                      \
                Sk_[s - 1] += kk ? (S2) : 0.0f;                      \
                Ss_[s - 1] += (tt && kk) ? (S2) : 0.0f;              \
            }

#pragma unroll
            for (int s = 1; s <= 8; ++s) {
                DO_COMP(tl.x, kl.x, s2x);
                DO_COMP(tl.y, kl.y, s2y);
                DO_COMP(tl.z, kl.z, s2z);
                DO_COMP(tl.w, kl.w, s2w);
            }
#undef DO_COMP
        }
    }

    // block reduction: wave shuffle -> LDS -> one atomicAdd per quantity
    __shared__ float red[4][NACC];
    const int lane = tid & 63;
    const int wv = tid >> 6;

#pragma unroll
    for (int s = 0; s < 8; ++s) {
        float v;
        v = wave_reduce_sum(St_[s]); if (lane == 0) red[wv][19 + s] = v;
        v = wave_reduce_sum(Sk_[s]); if (lane == 0) red[wv][28 + s] = v;
        v = wave_reduce_sum(Ss_[s]); if (lane == 0) red[wv][37 + s] = v;
    }
    {
        float v;
        v = wave_reduce_sum(rpg); if (lane == 0) red[wv][45] = v;
        v = wave_reduce_sum(rpp); if (lane == 0) red[wv][46] = v;
        v = wave_reduce_sum(rgg); if (lane == 0) red[wv][47] = v;
        v = wave_reduce_sum(kpg); if (lane == 0) red[wv][48] = v;
        v = wave_reduce_sum(kpp); if (lane == 0) red[wv][49] = v;
        v = wave_reduce_sum(kgg); if (lane == 0) red[wv][50] = v;
    }
    if (lane == 0) {
        // ballot counts are wave-uniform
#pragma unroll
        for (int s = 0; s < 8; ++s) {
            red[wv][1 + s] = (float)ct_[s];
            red[wv][10 + s] = (float)ck_[s];
        }
        red[wv][0] = 0.0f; red[wv][9] = 0.0f; red[wv][18] = 0.0f;
        red[wv][27] = 0.0f; red[wv][36] = 0.0f;
    }
    __syncthreads();
    if (tid < NACC) {
        float s = red[0][tid] + red[1][tid] + red[2][tid] + red[3][tid];
        atomicAdd(&ws[b * NACC + tid], s);
    }
}

__global__ __launch_bounds__(64) void pan_finalize(
    const float* __restrict__ ws, float* __restrict__ out)
{
    const int b = threadIdx.x;
    float dice_r = 0.0f, dice_k = 0.0f, lagg = 0.0f, ldis = 0.0f;

    if (b < NBATCH) {
        const float* w = ws + b * NACC;
        {
            float pg = w[45], pp = w[46], gg = w[47];
            dice_r = 1.0f - (2.0f * pg + EPSF) / ((pp + EPSF) + (gg + EPSF));
            pg = w[48]; pp = w[49]; gg = w[50];
            dice_k = 1.0f - (2.0f * pg + EPSF) / ((pp + EPSF) + (gg + EPSF));
        }
        float a[8];
#pragma unroll
        for (int i = 1; i < NSEG; ++i) {
            float ct = w[i], ck = w[NSEG + i];
            float St = w[2 * NSEG + i], Sk = w[3 * NSEG + i], Ss = w[4 * NSEG + i];
            float inv = 1.0f / (ck + 1.0f);
            float omi = 1.0f - inv;
            float n2 = omi * omi * Ss + (St - Ss) + inv * inv * (Sk - Ss);
            float nrm = sqrtf(n2);
            float d = nrm - 0.5f;  // SIGMA_AGG (no clamp — matches reference)
            lagg += logf(d * d + 1.0f) / (ct + 1.0f);
            float ckd = ck + 0.001f;
            a[i - 1] = Sk / (ckd * ckd);
        }
#pragma unroll
        for (int i = 0; i < 8; ++i) {
#pragma unroll
            for (int j = i + 1; j < 8; ++j) {
                float pair = 3.0f - sqrtf(a[i] + a[j]);  // SIGMA_DIS
                ldis += logf(pair * pair + 1.0f);
            }
        }
        ldis *= (1.0f / 56.0f);  // K_MAX*(K_MAX-1)
    }

    dice_r = wave_reduce_sum(dice_r);
    dice_k = wave_reduce_sum(dice_k);
    lagg = wave_reduce_sum(lagg);
    ldis = wave_reduce_sum(ldis);

    if (threadIdx.x == 0) {
        float loss = dice_r + 0.5f * dice_k + 0.25f * (lagg + ldis);
        out[0] = loss;
        out[1] = dice_r;
        out[2] = dice_k;
        out[3] = lagg;
        out[4] = ldis;
    }
}

extern "C" void kernel_launch(void* const* d_in, const int* in_sizes, int n_in,
                              void* d_out, int out_size, void* d_ws, size_t ws_size,
                              hipStream_t stream) {
    const float* pred_r = (const float*)d_in[0];
    const float* gt_r   = (const float*)d_in[1];
    const float* pred_k = (const float*)d_in[2];
    const float* gt_k   = (const float*)d_in[3];
    const float* sim    = (const float*)d_in[4];
    const int*   tlab   = (const int*)d_in[5];
    const int*   klab   = (const int*)d_in[6];
    float* out = (float*)d_out;
    float* ws  = (float*)d_ws;

    const int npix = in_sizes[0] / NBATCH;  // 640*640 = 409600
    const int nvec = npix >> 2;
    const int threads_per_batch = GX * 256;
    const int niter = (nvec + threads_per_batch - 1) / threads_per_batch;  // 4

    hipMemsetAsync(ws, 0, NBATCH * NACC * sizeof(float), stream);

    dim3 grid(GX, NBATCH);
    pan_main<<<grid, 256, 0, stream>>>(pred_r, gt_r, pred_k, gt_k, sim,
                                       tlab, klab, ws, npix, niter);
    pan_finalize<<<1, 64, 0, stream>>>(ws, out);
}

// Round 4
// 296.390 us; speedup vs baseline: 1.6197x; 1.0036x over previous
//
#include <hip/hip_runtime.h>
#include <math.h>

// PANLoss: dice(regions) + 0.5*dice(kernels) + 0.25*(agg + dis)
//
// R4: register accumulators + explicit 1-deep software pipeline.
//  - compile-time NITER=4, no bounds guard (exact divide) -> full unroll.
//  - iteration t+1's 10 float4 loads issued BEFORE iteration t is consumed:
//    ~10 KB outstanding per wave (R3 had ~2 loads in flight, VGPR_Count=40).
//  - __launch_bounds__(256,4): 128-VGPR budget; pipeline needs ~120.
//  - counts via __ballot/__popcll on the scalar pipe; segment 0 dropped.
//
// ws per batch (NACC=51 floats, slots 0,9,18,27,36 unused/zero):
//   [1..8] ct  [10..17] ck  [19..26] St  [28..35] Sk  [37..44] Ss
//   [45..47] regions pg/pp/gg   [48..50] kernels pg/pp/gg

#define NSEG 9
#define NACC 51
#define NBATCH 16
#define EPSF 1e-5f
#define GX 100
#define NITER 4  // 102400 float4 / (100*256) = exactly 4

__device__ __forceinline__ float wave_reduce_sum(float v) {
#pragma unroll
    for (int off = 32; off > 0; off >>= 1)
        v += __shfl_down(v, off, 64);
    return v;
}

__device__ __forceinline__ float sigm(float x) {
    return 1.0f / (1.0f + __expf(-x));
}

__global__ __launch_bounds__(256, 4) void pan_main(
    const float* __restrict__ pred_r, const float* __restrict__ gt_r,
    const float* __restrict__ pred_k, const float* __restrict__ gt_k,
    const float* __restrict__ sim,
    const int* __restrict__ tlab, const int* __restrict__ klab,
    float* __restrict__ ws, int npix)
{
    const int tid = threadIdx.x;
    const int b = blockIdx.y;
    const long long base = (long long)b * npix;
    const long long sbase = (long long)b * 4 * npix;

    const float4* pr4 = (const float4*)(pred_r + base);
    const float4* gr4 = (const float4*)(gt_r + base);
    const float4* pk4 = (const float4*)(pred_k + base);
    const float4* gk4 = (const float4*)(gt_k + base);
    const float4* c0_4 = (const float4*)(sim + sbase);
    const float4* c1_4 = (const float4*)(sim + sbase + npix);
    const float4* c2_4 = (const float4*)(sim + sbase + 2LL * npix);
    const float4* c3_4 = (const float4*)(sim + sbase + 3LL * npix);
    const int4* tl4 = (const int4*)(tlab + base);
    const int4* kl4 = (const int4*)(klab + base);

    float St_[8], Sk_[8], Ss_[8];
    unsigned ct_[8], ck_[8];
#pragma unroll
    for (int s = 0; s < 8; ++s) {
        St_[s] = 0.0f; Sk_[s] = 0.0f; Ss_[s] = 0.0f;
        ct_[s] = 0u; ck_[s] = 0u;
    }
    float rpg = 0.0f, rpp = 0.0f, rgg = 0.0f;
    float kpg = 0.0f, kpp = 0.0f, kgg = 0.0f;

    int i = blockIdx.x * blockDim.x + tid;
    const int stride = GX * 256;

    // prologue: load iteration 0
    float4 pr = pr4[i], gr = gr4[i], pk = pk4[i], gk = gk4[i];
    float4 c0 = c0_4[i], c1 = c1_4[i], c2 = c2_4[i], c3 = c3_4[i];
    int4 tl = tl4[i], kl = kl4[i];

#pragma unroll
    for (int t = 0; t < NITER; ++t) {
        // issue next iteration's loads before consuming current registers
        float4 n_pr, n_gr, n_pk, n_gk, n_c0, n_c1, n_c2, n_c3;
        int4 n_tl, n_kl;
        if (t + 1 < NITER) {
            const int j = i + stride;
            n_pr = pr4[j]; n_gr = gr4[j]; n_pk = pk4[j]; n_gk = gk4[j];
            n_c0 = c0_4[j]; n_c1 = c1_4[j]; n_c2 = c2_4[j]; n_c3 = c3_4[j];
            n_tl = tl4[j]; n_kl = kl4[j];
        }

        // ---- consume current ----
        {
            float p;
            p = sigm(pr.x); rpg += p * gr.x; rpp += p * p; rgg += gr.x;
            p = sigm(pr.y); rpg += p * gr.y; rpp += p * p; rgg += gr.y;
            p = sigm(pr.z); rpg += p * gr.z; rpp += p * p; rgg += gr.z;
            p = sigm(pr.w); rpg += p * gr.w; rpp += p * p; rgg += gr.w;
            p = sigm(pk.x); kpg += p * gk.x; kpp += p * p; kgg += gk.x;
            p = sigm(pk.y); kpg += p * gk.y; kpp += p * p; kgg += gk.y;
            p = sigm(pk.z); kpg += p * gk.z; kpp += p * p; kgg += gk.z;
            p = sigm(pk.w); kpg += p * gk.w; kpp += p * p; kgg += gk.w;
        }

        float s2x = c0.x * c0.x + c1.x * c1.x + c2.x * c2.x + c3.x * c3.x;
        float s2y = c0.y * c0.y + c1.y * c1.y + c2.y * c2.y + c3.y * c3.y;
        float s2z = c0.z * c0.z + c1.z * c1.z + c2.z * c2.z + c3.z * c3.z;
        float s2w = c0.w * c0.w + c1.w * c1.w + c2.w * c2.w + c3.w * c3.w;

#define DO_COMP(TL, KL, S2)                                          \
        {                                                            \
            bool tt = ((TL) == s);                                   \
            bool kk = ((KL) == s);                                   \
            ct_[s - 1] += (unsigned)__popcll(__ballot(tt));          \
            ck_[s - 1] += (unsigned)__popcll(__ballot(kk));          \
            St_[s - 1] += tt ? (S2) : 0.0f;                          \
            Sk_[s - 1] += kk ? (S2) : 0.0f;                          \
            Ss_[s - 1] += (tt && kk) ? (S2) : 0.0f;                  \
        }

#pragma unroll
        for (int s = 1; s <= 8; ++s) {
            DO_COMP(tl.x, kl.x, s2x);
            DO_COMP(tl.y, kl.y, s2y);
            DO_COMP(tl.z, kl.z, s2z);
            DO_COMP(tl.w, kl.w, s2w);
        }
#undef DO_COMP

        // rotate pipeline registers
        if (t + 1 < NITER) {
            pr = n_pr; gr = n_gr; pk = n_pk; gk = n_gk;
            c0 = n_c0; c1 = n_c1; c2 = n_c2; c3 = n_c3;
            tl = n_tl; kl = n_kl;
            i += stride;
        }
    }

    // block reduction: wave shuffle -> LDS -> one atomicAdd per quantity
    __shared__ float red[4][NACC];
    const int lane = tid & 63;
    const int wv = tid >> 6;

#pragma unroll
    for (int s = 0; s < 8; ++s) {
        float v;
        v = wave_reduce_sum(St_[s]); if (lane == 0) red[wv][19 + s] = v;
        v = wave_reduce_sum(Sk_[s]); if (lane == 0) red[wv][28 + s] = v;
        v = wave_reduce_sum(Ss_[s]); if (lane == 0) red[wv][37 + s] = v;
    }
    {
        float v;
        v = wave_reduce_sum(rpg); if (lane == 0) red[wv][45] = v;
        v = wave_reduce_sum(rpp); if (lane == 0) red[wv][46] = v;
        v = wave_reduce_sum(rgg); if (lane == 0) red[wv][47] = v;
        v = wave_reduce_sum(kpg); if (lane == 0) red[wv][48] = v;
        v = wave_reduce_sum(kpp); if (lane == 0) red[wv][49] = v;
        v = wave_reduce_sum(kgg); if (lane == 0) red[wv][50] = v;
    }
    if (lane == 0) {
#pragma unroll
        for (int s = 0; s < 8; ++s) {
            red[wv][1 + s] = (float)ct_[s];
            red[wv][10 + s] = (float)ck_[s];
        }
        red[wv][0] = 0.0f; red[wv][9] = 0.0f; red[wv][18] = 0.0f;
        red[wv][27] = 0.0f; red[wv][36] = 0.0f;
    }
    __syncthreads();
    if (tid < NACC) {
        float s = red[0][tid] + red[1][tid] + red[2][tid] + red[3][tid];
        atomicAdd(&ws[b * NACC + tid], s);
    }
}

__global__ __launch_bounds__(64) void pan_finalize(
    const float* __restrict__ ws, float* __restrict__ out)
{
    const int b = threadIdx.x;
    float dice_r = 0.0f, dice_k = 0.0f, lagg = 0.0f, ldis = 0.0f;

    if (b < NBATCH) {
        const float* w = ws + b * NACC;
        {
            float pg = w[45], pp = w[46], gg = w[47];
            dice_r = 1.0f - (2.0f * pg + EPSF) / ((pp + EPSF) + (gg + EPSF));
            pg = w[48]; pp = w[49]; gg = w[50];
            dice_k = 1.0f - (2.0f * pg + EPSF) / ((pp + EPSF) + (gg + EPSF));
        }
        float a[8];
#pragma unroll
        for (int i = 1; i < NSEG; ++i) {
            float ct = w[i], ck = w[NSEG + i];
            float St = w[2 * NSEG + i], Sk = w[3 * NSEG + i], Ss = w[4 * NSEG + i];
            float inv = 1.0f / (ck + 1.0f);
            float omi = 1.0f - inv;
            float n2 = omi * omi * Ss + (St - Ss) + inv * inv * (Sk - Ss);
            float nrm = sqrtf(n2);
            float d = nrm - 0.5f;  // SIGMA_AGG (no clamp — matches reference)
            lagg += logf(d * d + 1.0f) / (ct + 1.0f);
            float ckd = ck + 0.001f;
            a[i - 1] = Sk / (ckd * ckd);
        }
#pragma unroll
        for (int i = 0; i < 8; ++i) {
#pragma unroll
            for (int j = i + 1; j < 8; ++j) {
                float pair = 3.0f - sqrtf(a[i] + a[j]);  // SIGMA_DIS
                ldis += logf(pair * pair + 1.0f);
            }
        }
        ldis *= (1.0f / 56.0f);  // K_MAX*(K_MAX-1)
    }

    dice_r = wave_reduce_sum(dice_r);
    dice_k = wave_reduce_sum(dice_k);
    lagg = wave_reduce_sum(lagg);
    ldis = wave_reduce_sum(ldis);

    if (threadIdx.x == 0) {
        float loss = dice_r + 0.5f * dice_k + 0.25f * (lagg + ldis);
        out[0] = loss;
        out[1] = dice_r;
        out[2] = dice_k;
        out[3] = lagg;
        out[4] = ldis;
    }
}

extern "C" void kernel_launch(void* const* d_in, const int* in_sizes, int n_in,
                              void* d_out, int out_size, void* d_ws, size_t ws_size,
                              hipStream_t stream) {
    const float* pred_r = (const float*)d_in[0];
    const float* gt_r   = (const float*)d_in[1];
    const float* pred_k = (const float*)d_in[2];
    const float* gt_k   = (const float*)d_in[3];
    const float* sim    = (const float*)d_in[4];
    const int*   tlab   = (const int*)d_in[5];
    const int*   klab   = (const int*)d_in[6];
    float* out = (float*)d_out;
    float* ws  = (float*)d_ws;

    const int npix = in_sizes[0] / NBATCH;  // 640*640 = 409600

    hipMemsetAsync(ws, 0, NBATCH * NACC * sizeof(float), stream);

    dim3 grid(GX, NBATCH);
    pan_main<<<grid, 256, 0, stream>>>(pred_r, gt_r, pred_k, gt_k, sim,
                                       tlab, klab, ws, npix);
    pan_finalize<<<1, 64, 0, stream>>>(ws, out);
}

// Round 5
// 284.349 us; speedup vs baseline: 1.6883x; 1.0423x over previous
//
#include <hip/hip_runtime.h>
#include <math.h>

// PANLoss: dice(regions) + 0.5*dice(kernels) + 0.25*(agg + dis)
//
// R5: max thread-level parallelism. NITER=1 — each thread processes exactly
// one float4 pixel-group: 10 independent loads issued together, one consume,
// exit. Grid = 400x16 = 6400 blocks (25/CU of work) so the memory system sees
// 20+ resident waves/CU each with ~10KB outstanding. No software pipelining
// for the compiler to defeat (R3/R4 lesson: it recycles VGPRs and drains
// vmcnt every iteration regardless of source-level structure).
//
// ws per batch (NACC=51 floats, slots 0,9,18,27,36 unused/zero):
//   [1..8] ct  [10..17] ck  [19..26] St  [28..35] Sk  [37..44] Ss
//   [45..47] regions pg/pp/gg   [48..50] kernels pg/pp/gg

#define NSEG 9
#define NACC 51
#define NBATCH 16
#define EPSF 1e-5f
#define BPB 400  // blocks per batch: 102400 float4 / 256 = 400 exact

__device__ __forceinline__ float wave_reduce_sum(float v) {
#pragma unroll
    for (int off = 32; off > 0; off >>= 1)
        v += __shfl_down(v, off, 64);
    return v;
}

__device__ __forceinline__ float sigm(float x) {
    return 1.0f / (1.0f + __expf(-x));
}

__global__ __launch_bounds__(256) void pan_main(
    const float* __restrict__ pred_r, const float* __restrict__ gt_r,
    const float* __restrict__ pred_k, const float* __restrict__ gt_k,
    const float* __restrict__ sim,
    const int* __restrict__ tlab, const int* __restrict__ klab,
    float* __restrict__ ws, int npix)
{
    const int tid = threadIdx.x;
    const int b = blockIdx.y;
    const int i = blockIdx.x * 256 + tid;
    const long long base = (long long)b * npix;
    const long long sbase = (long long)b * 4 * npix;

    // ---- issue all 10 independent loads back-to-back ----
    const float4 pr = ((const float4*)(pred_r + base))[i];
    const float4 gr = ((const float4*)(gt_r + base))[i];
    const float4 pk = ((const float4*)(pred_k + base))[i];
    const float4 gk = ((const float4*)(gt_k + base))[i];
    const float4 c0 = ((const float4*)(sim + sbase))[i];
    const float4 c1 = ((const float4*)(sim + sbase + npix))[i];
    const float4 c2 = ((const float4*)(sim + sbase + 2LL * npix))[i];
    const float4 c3 = ((const float4*)(sim + sbase + 3LL * npix))[i];
    const int4 tl = ((const int4*)(tlab + base))[i];
    const int4 kl = ((const int4*)(klab + base))[i];

    // ---- dice sums (g in {0,1} so g*g == g) ----
    float rpg, rpp, rgg, kpg, kpp, kgg;
    {
        float p;
        p = sigm(pr.x); rpg  = p * gr.x; rpp  = p * p; rgg  = gr.x;
        p = sigm(pr.y); rpg += p * gr.y; rpp += p * p; rgg += gr.y;
        p = sigm(pr.z); rpg += p * gr.z; rpp += p * p; rgg += gr.z;
        p = sigm(pr.w); rpg += p * gr.w; rpp += p * p; rgg += gr.w;
        p = sigm(pk.x); kpg  = p * gk.x; kpp  = p * p; kgg  = gk.x;
        p = sigm(pk.y); kpg += p * gk.y; kpp += p * p; kgg += gk.y;
        p = sigm(pk.z); kpg += p * gk.z; kpp += p * p; kgg += gk.z;
        p = sigm(pk.w); kpg += p * gk.w; kpp += p * p; kgg += gk.w;
    }

    const float s2x = c0.x * c0.x + c1.x * c1.x + c2.x * c2.x + c3.x * c3.x;
    const float s2y = c0.y * c0.y + c1.y * c1.y + c2.y * c2.y + c3.y * c3.y;
    const float s2z = c0.z * c0.z + c1.z * c1.z + c2.z * c2.z + c3.z * c3.z;
    const float s2w = c0.w * c0.w + c1.w * c1.w + c2.w * c2.w + c3.w * c3.w;

    float St_[8], Sk_[8], Ss_[8];
    unsigned ct_[8], ck_[8];

#define DO_COMP(TL, KL, S2, OP)                                      \
    {                                                                \
        bool tt = ((TL) == s);                                       \
        bool kk = ((KL) == s);                                       \
        ct_[s - 1] OP (unsigned)__popcll(__ballot(tt));              \
        ck_[s - 1] OP (unsigned)__popcll(__ballot(kk));              \
        St_[s - 1] OP tt ? (S2) : 0.0f;                              \
        Sk_[s - 1] OP kk ? (S2) : 0.0f;                              \
        Ss_[s - 1] OP (tt && kk) ? (S2) : 0.0f;                      \
    }

#pragma unroll
    for (int s = 1; s <= 8; ++s) {
        DO_COMP(tl.x, kl.x, s2x, =);
        DO_COMP(tl.y, kl.y, s2y, +=);
        DO_COMP(tl.z, kl.z, s2z, +=);
        DO_COMP(tl.w, kl.w, s2w, +=);
    }
#undef DO_COMP

    // ---- block reduction: wave shuffle -> LDS -> one atomicAdd per qty ----
    __shared__ float red[4][NACC];
    const int lane = tid & 63;
    const int wv = tid >> 6;

#pragma unroll
    for (int s = 0; s < 8; ++s) {
        float v;
        v = wave_reduce_sum(St_[s]); if (lane == 0) red[wv][19 + s] = v;
        v = wave_reduce_sum(Sk_[s]); if (lane == 0) red[wv][28 + s] = v;
        v = wave_reduce_sum(Ss_[s]); if (lane == 0) red[wv][37 + s] = v;
    }
    {
        float v;
        v = wave_reduce_sum(rpg); if (lane == 0) red[wv][45] = v;
        v = wave_reduce_sum(rpp); if (lane == 0) red[wv][46] = v;
        v = wave_reduce_sum(rgg); if (lane == 0) red[wv][47] = v;
        v = wave_reduce_sum(kpg); if (lane == 0) red[wv][48] = v;
        v = wave_reduce_sum(kpp); if (lane == 0) red[wv][49] = v;
        v = wave_reduce_sum(kgg); if (lane == 0) red[wv][50] = v;
    }
    if (lane == 0) {
        // ballot counts are wave-uniform
#pragma unroll
        for (int s = 0; s < 8; ++s) {
            red[wv][1 + s] = (float)ct_[s];
            red[wv][10 + s] = (float)ck_[s];
        }
        red[wv][0] = 0.0f; red[wv][9] = 0.0f; red[wv][18] = 0.0f;
        red[wv][27] = 0.0f; red[wv][36] = 0.0f;
    }
    __syncthreads();
    if (tid < NACC) {
        float s = red[0][tid] + red[1][tid] + red[2][tid] + red[3][tid];
        atomicAdd(&ws[b * NACC + tid], s);
    }
}

__global__ __launch_bounds__(64) void pan_finalize(
    const float* __restrict__ ws, float* __restrict__ out)
{
    const int b = threadIdx.x;
    float dice_r = 0.0f, dice_k = 0.0f, lagg = 0.0f, ldis = 0.0f;

    if (b < NBATCH) {
        const float* w = ws + b * NACC;
        {
            float pg = w[45], pp = w[46], gg = w[47];
            dice_r = 1.0f - (2.0f * pg + EPSF) / ((pp + EPSF) + (gg + EPSF));
            pg = w[48]; pp = w[49]; gg = w[50];
            dice_k = 1.0f - (2.0f * pg + EPSF) / ((pp + EPSF) + (gg + EPSF));
        }
        float a[8];
#pragma unroll
        for (int i = 1; i < NSEG; ++i) {
            float ct = w[i], ck = w[NSEG + i];
            float St = w[2 * NSEG + i], Sk = w[3 * NSEG + i], Ss = w[4 * NSEG + i];
            float inv = 1.0f / (ck + 1.0f);
            float omi = 1.0f - inv;
            float n2 = omi * omi * Ss + (St - Ss) + inv * inv * (Sk - Ss);
            float nrm = sqrtf(n2);
            float d = nrm - 0.5f;  // SIGMA_AGG (no clamp — matches reference)
            lagg += logf(d * d + 1.0f) / (ct + 1.0f);
            float ckd = ck + 0.001f;
            a[i - 1] = Sk / (ckd * ckd);
        }
#pragma unroll
        for (int i = 0; i < 8; ++i) {
#pragma unroll
            for (int j = i + 1; j < 8; ++j) {
                float pair = 3.0f - sqrtf(a[i] + a[j]);  // SIGMA_DIS
                ldis += logf(pair * pair + 1.0f);
            }
        }
        ldis *= (1.0f / 56.0f);  // K_MAX*(K_MAX-1)
    }

    dice_r = wave_reduce_sum(dice_r);
    dice_k = wave_reduce_sum(dice_k);
    lagg = wave_reduce_sum(lagg);
    ldis = wave_reduce_sum(ldis);

    if (threadIdx.x == 0) {
        float loss = dice_r + 0.5f * dice_k + 0.25f * (lagg + ldis);
        out[0] = loss;
        out[1] = dice_r;
        out[2] = dice_k;
        out[3] = lagg;
        out[4] = ldis;
    }
}

extern "C" void kernel_launch(void* const* d_in, const int* in_sizes, int n_in,
                              void* d_out, int out_size, void* d_ws, size_t ws_size,
                              hipStream_t stream) {
    const float* pred_r = (const float*)d_in[0];
    const float* gt_r   = (const float*)d_in[1];
    const float* pred_k = (const float*)d_in[2];
    const float* gt_k   = (const float*)d_in[3];
    const float* sim    = (const float*)d_in[4];
    const int*   tlab   = (const int*)d_in[5];
    const int*   klab   = (const int*)d_in[6];
    float* out = (float*)d_out;
    float* ws  = (float*)d_ws;

    const int npix = in_sizes[0] / NBATCH;  // 640*640 = 409600

    hipMemsetAsync(ws, 0, NBATCH * NACC * sizeof(float), stream);

    dim3 grid(BPB, NBATCH);
    pan_main<<<grid, 256, 0, stream>>>(pred_r, gt_r, pred_k, gt_k, sim,
                                       tlab, klab, ws, npix);
    pan_finalize<<<1, 64, 0, stream>>>(ws, out);
}